// Round 6
// baseline (3104.102 us; speedup 1.0000x reference)
//
#include <hip/hip_runtime.h>
#include <cstdint>

// LSTM decoder: B=64, S=512, D=512, H=512.
// 8 clusters (blockIdx%8) x 32 WGs; cluster owns 8 batches. WG owns 16 hidden
// units (all 4 gates); W_ih/W_hh slices live in VGPRs as bf16 MFMA A-frags.
// R10: tag-in-line dataflow sync. R8/R9 lesson: vmcnt retires in ISSUE order,
// so any drain/flag-poll serializes behind every older in-flight op. Remove
// the sync fabric entirely:
//  - h slot = 16B {8B packed bf16 (4 units), 8B tag = step+1}. Producer:
//    data stq, compiler barrier, tag stq (same wave, same 64B line ->
//    serviced in issue order: tag visible => data visible).
//  - consumer polls the slot tags DIRECTLY (detection == data fetch, one L2
//    RT). Batched per iteration: all tag loads, barrier, all data loads,
//    then checks -> single RT per poll iteration, pipelined.
//  - NO drain_vm, NO flag array, NO __syncthreads in the steady loop.
//    Out-transpose via 4 intra-wave shfl + one 16B store (quad0 lanes).
//  - x path = R6 tail (global loads force-retired by x-MFMAs, in post-publish
//    slack). No LDS staging (R9 regression).
//  - parity-2 hbuf + monotone tags: slot in parity p holds tag t+1, next use
//    t+3 -> no ABA; hbuf memset per launch so stale tags (>=1) never match.

#define SS 512
#define DD 512
#define HH 512

typedef __attribute__((ext_vector_type(8))) short s8;
typedef __attribute__((ext_vector_type(4))) float f4;

__device__ inline short f2bf(float f) {
  unsigned u = __float_as_uint(f);
  u += 0x7fffu + ((u >> 16) & 1u);   // RNE
  return (short)(u >> 16);
}

__device__ inline s8 cvt8(f4 a, f4 b) {
  s8 v;
  v[0]=f2bf(a[0]); v[1]=f2bf(a[1]); v[2]=f2bf(a[2]); v[3]=f2bf(a[3]);
  v[4]=f2bf(b[0]); v[5]=f2bf(b[1]); v[6]=f2bf(b[2]); v[7]=f2bf(b[3]);
  return v;
}

__device__ inline float sigm(float x)  { return 1.f / (1.f + __expf(-x)); }
__device__ inline float tanh_f(float x){ return 1.f - 2.f / (__expf(2.f*x) + 1.f); }

__device__ inline void stq_agent(void* p, unsigned long long v) {
  __hip_atomic_store((unsigned long long*)p, v, __ATOMIC_RELAXED, __HIP_MEMORY_SCOPE_AGENT);
}
__device__ inline unsigned long long ldq_agent(const void* p) {
  return __hip_atomic_load((const unsigned long long*)p, __ATOMIC_RELAXED, __HIP_MEMORY_SCOPE_AGENT);
}
__device__ inline unsigned ld4_agent(const unsigned* p) {
  return __hip_atomic_load(p, __ATOMIC_RELAXED, __HIP_MEMORY_SCOPE_AGENT);
}
__device__ inline void drain_vm() {
  asm volatile("s_waitcnt vmcnt(0)" ::: "memory");
}
__device__ inline unsigned long long tagpair(unsigned t) {
  return (unsigned long long)t * 0x0000000100000001ull;
}

// Heavy barrier (ONCE, after phase A): release fence + counter + acquire.
__device__ inline void heavy_barrier(unsigned* cnt, unsigned target) {
  drain_vm();
  __syncthreads();
  if (threadIdx.x == 0) {
    __threadfence();
    __hip_atomic_fetch_add(cnt, 1u, __ATOMIC_RELAXED, __HIP_MEMORY_SCOPE_AGENT);
    unsigned guard = 0;
    while (__hip_atomic_load(cnt, __ATOMIC_RELAXED, __HIP_MEMORY_SCOPE_AGENT) < target) {
      __builtin_amdgcn_s_sleep(2);
      if (++guard > 10000000u) break;
    }
  }
  __syncthreads();
  (void)__hip_atomic_load(cnt, __ATOMIC_ACQUIRE, __HIP_MEMORY_SCOPE_AGENT);
  __syncthreads();
}

__launch_bounds__(256, 1)
__global__ void lstm_kernel(const float* __restrict__ x,   const float* __restrict__ emb,
                            const float* __restrict__ h_n, const float* __restrict__ c_n,
                            const float* __restrict__ W_ih, const float* __restrict__ W_hh,
                            const float* __restrict__ b_ih, const float* __restrict__ b_hh,
                            float* __restrict__ out, char* __restrict__ ws)
{
  const int tid  = threadIdx.x;
  const int wave = tid >> 6, lane = tid & 63;
  const int quad = lane >> 4, n = lane & 15;       // n = batch column (8 real + 8 pad)
  const int c  = blockIdx.x & 7;                   // cluster
  const int wg = blockIdx.x >> 3;                  // 0..31 within cluster

  unsigned* cnt  = (unsigned*)(ws + (size_t)c * 128);
  char*     hbuf = ws + 4096;                      // [2][8][16KB] tagged h slots
  char*     xfrag = ws + 4096 + 2*8*16384;         // [8][512][8KB] compact x
  char*     xfc   = xfrag + (size_t)c * ((size_t)SS * 8192);

  // ---- Phase A1: (emb ++ x[:, :-1]) -> compact bf16 B-frag layout ----
  {
    int widc = wg*4 + wave;                        // 0..127 warps in cluster
    for (int item = widc; item < 4096; item += 128) {
      int t = item & 511, bl = item >> 9;          // bl 0..7 (real batches only)
      const float* src = (t == 0) ? (emb + (size_t)(c*8 + bl) * DD)
                                  : (x + ((size_t)(c*8 + bl) * SS + (t-1)) * DD);
      f4 f0 = *(const f4*)(src + lane*8);
      f4 f1 = *(const f4*)(src + lane*8 + 4);
      s8 v = cvt8(f0, f1);
      // element (k=lane*8+j, col=bl) at (k>>5)*512 + ((k>>3)&3)*128 + bl*16 + (k&7)*2
      *(s8*)(xfc + (size_t)t*8192 + (lane>>2)*512 + (lane&3)*128 + bl*16) = v;
    }
  }

  // ---- Phase A2: W_ih/W_hh slices -> register A-fragments (bf16) ----
  s8 wihf[16], whhf[16];
  {
    int r = wave*16 + n;                           // row in WG's 64-row slice
    int rowg = (r & 3)*512 + wg*16 + (r >> 2);     // gate-major row in W
    const float* pih = W_ih + (size_t)rowg * DD + quad*8;
    const float* phh = W_hh + (size_t)rowg * HH + quad*8;
#pragma unroll
    for (int kk = 0; kk < 16; ++kk) {
      f4 a0 = *(const f4*)(pih + kk*32);
      f4 a1 = *(const f4*)(pih + kk*32 + 4);
      wihf[kk] = cvt8(a0, a1);
      f4 b0 = *(const f4*)(phh + kk*32);
      f4 b1 = *(const f4*)(phh + kk*32 + 4);
      whhf[kk] = cvt8(b0, b1);
    }
  }

  // ---- Phase A3: lane-private state. Lane updates unit u, batch n. ----
  const int u = wg*16 + wave*4 + quad;
  f4 biasv;
  biasv[0] = b_ih[0*512+u] + b_hh[0*512+u];        // i
  biasv[1] = b_ih[1*512+u] + b_hh[1*512+u];        // f
  biasv[2] = b_ih[2*512+u] + b_hh[2*512+u];        // g
  biasv[3] = b_ih[3*512+u] + b_hh[3*512+u];        // o
  float creg = 0.f, h0 = 0.f;
  if (n < 8) {
    creg = c_n[(size_t)(c*8 + n)*HH + u];
    h0   = h_n[(size_t)(c*8 + n)*HH + u];
  }
  // producer slot base for this wave's 4 units: slot(kk,q8,col)=kk*1024+q8*128+col*16
  const int u0 = wg*16 + wave*4;
  const int pslot = (u0 >> 5)*1024 + ((u0 >> 2) & 7)*128;   // + lane*16

  // h0 -> parity-0 buffer, tag = 1 (h_t carries tag t+1)
  {
    int sv = (int)(unsigned short)f2bf(h0);
    int p2 = sv | (__shfl_xor(sv, 16) << 16);      // quads 0,1 of col n=lane
    int p4 = __shfl_xor(p2, 32);                   // quads 2,3
    unsigned long long packed = (unsigned)p2 | ((unsigned long long)(unsigned)p4 << 32);
    if (lane < 8) {
      char* s = hbuf + (size_t)c*16384 + pslot + lane*16;
      stq_agent(s, packed);
      asm volatile("" ::: "memory");
      stq_agent(s + 8, tagpair(1u));
    }
  }

  heavy_barrier(cnt, 32u);                         // phase A visible everywhere

  const s8 zero8 = {0,0,0,0,0,0,0,0};
  s8 xf[16], hf[16];
#pragma unroll
  for (int kk = 0; kk < 16; ++kk) { xf[kk] = zero8; hf[kk] = zero8; }  // pad lanes stay 0

  // x-GEMM for t=0 (xfrag coherent after heavy barrier)
  f4 accx = biasv, accx2 = {0.f,0.f,0.f,0.f};
  if (n < 8) {
    const char* xb = xfc + quad*128 + n*16;
#pragma unroll
    for (int kk = 0; kk < 16; ++kk)
      xf[kk] = *(const s8*)(xb + kk*512);
  }
#pragma unroll
  for (int kk = 0; kk < 8; ++kk)
    accx  = __builtin_amdgcn_mfma_f32_16x16x32_bf16(wihf[kk],   xf[kk],   accx,  0,0,0);
#pragma unroll
  for (int kk = 0; kk < 8; ++kk)
    accx2 = __builtin_amdgcn_mfma_f32_16x16x32_bf16(wihf[kk+8], xf[kk+8], accx2, 0,0,0);

  // hf preload for t=0 (h_0 ready via heavy barrier; tags known good)
  unsigned pm = 0xFFFFu;                           // chunk kk resident in hf[kk]
  if (n < 8) {
    const char* cb = hbuf + (size_t)c*16384 + quad*256 + n*16;
#pragma unroll
    for (int kk = 0; kk < 16; ++kk) {
      union { unsigned long long qq[2]; s8 v; } tmp;
      tmp.qq[0] = ldq_agent(cb + kk*1024);
      tmp.qq[1] = ldq_agent(cb + kk*1024 + 128);
      hf[kk] = tmp.v;
    }
  }

  for (int t = 0; t < SS; ++t) {
    const char* hrd = hbuf + (size_t)(((t  )&1)*8 + c)*16384;
    char*       hwr = hbuf + (size_t)(((t+1)&1)*8 + c)*16384;
    const unsigned T = (unsigned)t + 1u;           // h_t tag

    // ---- pass 1: spin on missing chunks' tags (tags ARE the flags) ----
    if (pm != 0xFFFFu) {
      const char* cb = hrd + quad*256 + n*16;
      unsigned guard = 0;
      while (!__all(pm == 0xFFFFu)) {
        if (n < 8 && pm != 0xFFFFu) {
          unsigned tA[16], tB[16];
          unsigned long long dA[16], dB[16];
#pragma unroll
          for (int kk = 0; kk < 16; ++kk)
            if (!(pm & (1u << kk))) {
              tA[kk] = ld4_agent((const unsigned*)(cb + kk*1024 + 8));
              tB[kk] = ld4_agent((const unsigned*)(cb + kk*1024 + 136));
            }
          asm volatile("" ::: "memory");           // tags issued before data
#pragma unroll
          for (int kk = 0; kk < 16; ++kk)
            if (!(pm & (1u << kk))) {
              dA[kk] = ldq_agent(cb + kk*1024);
              dB[kk] = ldq_agent(cb + kk*1024 + 128);
            }
#pragma unroll
          for (int kk = 0; kk < 16; ++kk)
            if (!(pm & (1u << kk)) && tA[kk] == T && tB[kk] == T) {
              union { unsigned long long qq[2]; s8 v; } tmp;
              tmp.qq[0] = dA[kk]; tmp.qq[1] = dB[kk];
              hf[kk] = tmp.v;
              pm |= 1u << kk;
            }
        }
        if (++guard > 200000u) break;              // anti-hang failsafe
      }
    }

    // ---- h-GEMM ----
    f4 acc = accx, acc2 = accx2;
#pragma unroll
    for (int kk = 0; kk < 8; ++kk)
      acc  = __builtin_amdgcn_mfma_f32_16x16x32_bf16(whhf[kk],   hf[kk],   acc,  0,0,0);
#pragma unroll
    for (int kk = 0; kk < 8; ++kk)
      acc2 = __builtin_amdgcn_mfma_f32_16x16x32_bf16(whhf[kk+8], hf[kk+8], acc2, 0,0,0);
    acc += acc2;

    // lane holds all 4 gates of (u, n): reg0=i, reg1=f, reg2=g, reg3=o
    float iv = sigm(acc[0]);
    float fv = sigm(acc[1]);
    float gv = tanh_f(acc[2]);
    float ov = sigm(acc[3]);
    creg = fv*creg + iv*gv;
    float hv = ov * tanh_f(creg);

    // ---- publish h_{t+1}: data store, barrier, tag store. No drain. ----
    if (t < SS-1) {
      int sv = (int)(unsigned short)f2bf(hv);
      int p2 = sv | (__shfl_xor(sv, 16) << 16);
      int p4 = __shfl_xor(p2, 32);
      unsigned long long packed = (unsigned)p2 | ((unsigned long long)(unsigned)p4 << 32);
      if (lane < 8) {
        char* s = hwr + pslot + lane*16;
        stq_agent(s, packed);
        asm volatile("" ::: "memory");             // data before tag (same line)
        stq_agent(s + 8, tagpair((unsigned)t + 2u));
        asm volatile("" ::: "memory");             // pin tag store here
      }
    }

    // ---- out store: 4-shfl gather -> one 16B f4 per (b, 4-unit slice) ----
    {
      float o0 = __shfl(hv, n);
      float o1 = __shfl(hv, 16 + n);
      float o2 = __shfl(hv, 32 + n);
      float o3 = __shfl(hv, 48 + n);
      if (quad == 0 && n < 8) {
        f4 o; o[0]=o0; o[1]=o1; o[2]=o2; o[3]=o3;
        *(f4*)(out + ((size_t)(c*8 + n)*SS + t)*HH + u0) = o;
      }
    }

    if (t < SS-1) {
      // ---- x-GEMM for t+1 (global loads, force-retired by the MFMAs) ----
      if (n < 8) {
        const char* xb = xfc + (size_t)(t+1)*8192 + quad*128 + n*16;
#pragma unroll
        for (int kk = 0; kk < 16; ++kk)
          xf[kk] = *(const s8*)(xb + kk*512);
      }
      accx = biasv; accx2[0]=0.f; accx2[1]=0.f; accx2[2]=0.f; accx2[3]=0.f;
#pragma unroll
      for (int kk = 0; kk < 8; ++kk)
        accx  = __builtin_amdgcn_mfma_f32_16x16x32_bf16(wihf[kk],   xf[kk],   accx,  0,0,0);
#pragma unroll
      for (int kk = 0; kk < 8; ++kk)
        accx2 = __builtin_amdgcn_mfma_f32_16x16x32_bf16(wihf[kk+8], xf[kk+8], accx2, 0,0,0);

      // ---- opportunistic tagged prefetch for t+1 (one batched attempt) ----
      pm = 0xFFFFu;                                // pad lanes stay complete
      if (n < 8) {
        pm = 0u;
        const unsigned T2 = (unsigned)t + 2u;
        const char* cb = hwr + quad*256 + n*16;
        unsigned tA[16], tB[16];
        unsigned long long dA[16], dB[16];
#pragma unroll
        for (int kk = 0; kk < 16; ++kk) {
          tA[kk] = ld4_agent((const unsigned*)(cb + kk*1024 + 8));
          tB[kk] = ld4_agent((const unsigned*)(cb + kk*1024 + 136));
        }
        asm volatile("" ::: "memory");             // tags issued before data
#pragma unroll
        for (int kk = 0; kk < 16; ++kk) {
          dA[kk] = ldq_agent(cb + kk*1024);
          dB[kk] = ldq_agent(cb + kk*1024 + 128);
        }
#pragma unroll
        for (int kk = 0; kk < 16; ++kk)
          if (tA[kk] == T2 && tB[kk] == T2) {
            union { unsigned long long qq[2]; s8 v; } tmp;
            tmp.qq[0] = dA[kk]; tmp.qq[1] = dB[kk];
            hf[kk] = tmp.v;
            pm |= 1u << kk;
          }
      }
    }
  }
}

extern "C" void kernel_launch(void* const* d_in, const int* in_sizes, int n_in,
                              void* d_out, int out_size, void* d_ws, size_t ws_size,
                              hipStream_t stream) {
  const float* x    = (const float*)d_in[0];
  const float* emb  = (const float*)d_in[1];
  const float* h_n  = (const float*)d_in[2];
  const float* c_n  = (const float*)d_in[3];
  const float* W_ih = (const float*)d_in[4];
  const float* W_hh = (const float*)d_in[5];
  const float* b_ih = (const float*)d_in[6];
  const float* b_hh = (const float*)d_in[7];

  // zero barrier counters + ALL tagged h slots (stale tags from a previous
  // graph replay must never look valid; tags are >= 1).
  hipMemsetAsync(d_ws, 0, 4096 + 2*8*16384, stream);

  lstm_kernel<<<dim3(256), dim3(256), 0, stream>>>(
      x, emb, h_n, c_n, W_ih, W_hh, b_ih, b_hh, (float*)d_out, (char*)d_ws);
}